// Round 1
// baseline (188.904 us; speedup 1.0000x reference)
//
#include <hip/hip_runtime.h>
#include <math.h>

#define LB __launch_bounds__(256)

// scales: 0:{C=48,H=96,N=9216} 1:{96,48,2304} 2:{192,24,576} 3:{384,12,144}, B=2
// pixel-slot offsets (b-major within scale): {0, 18432, 23040, 24192}, total 24480
#define NSLOT 24480

struct QkvArgs {
  const float *x0, *x1, *x2, *x3;
  const float *w0, *w1, *w2, *w3;
  const float *c0, *c1, *c2, *c3;
  const float *wq[4], *bq[4], *wk[4], *bk[4], *wv[4], *bv[4];
  float *P, *V, *Q, *K;
};

__global__ LB void qkv_kernel(QkvArgs a) {
  __shared__ float s_w[3072];
  __shared__ float s_b[8], s_wq[8], s_wk[8], s_wv[64], s_bv[8];
  __shared__ float s_bq, s_bk;
  const int tid = threadIdx.x;
  const int bid = blockIdx.x;
  int scale, C, N, TOTs, slotoff, relblk;
  const float *xp, *wp, *bp;
  if (bid < 72)      { scale=0; C=48;  N=9216; TOTs=18432; slotoff=0;     relblk=bid;    xp=a.x0; wp=a.w0; bp=a.c0; }
  else if (bid < 90) { scale=1; C=96;  N=2304; TOTs=4608;  slotoff=18432; relblk=bid-72; xp=a.x1; wp=a.w1; bp=a.c1; }
  else if (bid < 95) { scale=2; C=192; N=576;  TOTs=1152;  slotoff=23040; relblk=bid-90; xp=a.x2; wp=a.w2; bp=a.c2; }
  else               { scale=3; C=384; N=144;  TOTs=288;   slotoff=24192; relblk=bid-95; xp=a.x3; wp=a.w3; bp=a.c3; }
  for (int i = tid; i < 8*C; i += 256) s_w[i] = wp[i];
  if (tid < 8) {
    s_b[tid]  = bp[tid];
    s_wq[tid] = a.wq[scale][tid];
    s_wk[tid] = a.wk[scale][tid];
    s_bv[tid] = a.bv[scale][tid];
  }
  if (tid < 64) s_wv[tid] = a.wv[scale][tid];
  if (tid == 0) { s_bq = a.bq[scale][0]; s_bk = a.bk[scale][0]; }
  __syncthreads();
  const int pix = relblk*256 + tid;
  if (pix >= TOTs) return;
  const int b = (pix >= N) ? 1 : 0;
  const int n = pix - b*N;
  float p[8];
  #pragma unroll
  for (int o = 0; o < 8; ++o) p[o] = s_b[o];
  const float* xb = xp + (size_t)b*C*N + n;
  for (int c = 0; c < C; ++c) {
    const float xv = xb[(size_t)c*N];
    #pragma unroll
    for (int o = 0; o < 8; ++o) p[o] = fmaf(s_w[o*C + c], xv, p[o]);
  }
  float q = s_bq, k = s_bk;
  #pragma unroll
  for (int c = 0; c < 8; ++c) { q = fmaf(s_wq[c], p[c], q); k = fmaf(s_wk[c], p[c], k); }
  float v[8];
  #pragma unroll
  for (int o = 0; o < 8; ++o) {
    float s = s_bv[o];
    #pragma unroll
    for (int c = 0; c < 8; ++c) s = fmaf(s_wv[o*8 + c], p[c], s);
    v[o] = s;
  }
  const int g = slotoff + pix;
  float4* Pp = (float4*)&a.P[(size_t)g*8];
  Pp[0] = make_float4(p[0], p[1], p[2], p[3]);
  Pp[1] = make_float4(p[4], p[5], p[6], p[7]);
  float4* Vp = (float4*)&a.V[(size_t)g*8];
  Vp[0] = make_float4(v[0], v[1], v[2], v[3]);
  Vp[1] = make_float4(v[4], v[5], v[6], v[7]);
  a.Q[g] = q; a.K[g] = k;
}

__global__ LB void kstat_kernel(const float* __restrict__ K, float* __restrict__ KST) {
  const int sb = blockIdx.x;              // 0..7  (scale*2 + b)
  const int scale = sb >> 1, b = sb & 1;
  int N, off;
  if (scale == 0)      { N = 9216; off = 0; }
  else if (scale == 1) { N = 2304; off = 18432; }
  else if (scale == 2) { N = 576;  off = 23040; }
  else                 { N = 144;  off = 24192; }
  const int base = off + b*N;
  const int tid = threadIdx.x;
  float mn = 1e30f, mx = -1e30f;
  for (int i = tid; i < N; i += 256) {
    const float v = K[base + i];
    mn = fminf(mn, v); mx = fmaxf(mx, v);
  }
  __shared__ float smn[256], smx[256];
  smn[tid] = mn; smx[tid] = mx;
  __syncthreads();
  for (int s = 128; s > 0; s >>= 1) {
    if (tid < s) { smn[tid] = fminf(smn[tid], smn[tid+s]); smx[tid] = fmaxf(smx[tid], smx[tid+s]); }
    __syncthreads();
  }
  if (tid == 0) { KST[sb*2] = smn[0]; KST[sb*2 + 1] = smx[0]; }
}

#define RQ 4
#define TK 512
__global__ LB void attn_kernel(const float* __restrict__ Q, const float* __restrict__ K,
                               const float* __restrict__ V, const float* __restrict__ KST,
                               float* __restrict__ PART, int S) {
  __shared__ __align__(16) float k_s[TK];
  __shared__ __align__(16) float v_s[TK*8];
  const int tid = threadIdx.x;
  const int bid = blockIdx.x;
  const int s0 = 18*S, s1 = 6*S, s2 = 2*S;
  int scale, rel, N, nqb, slotoff;
  if (bid < s0)              { scale=0; rel=bid;            N=9216; nqb=9; slotoff=0; }
  else if (bid < s0+s1)      { scale=1; rel=bid-s0;         N=2304; nqb=3; slotoff=18432; }
  else if (bid < s0+s1+s2)   { scale=2; rel=bid-s0-s1;      N=576;  nqb=1; slotoff=23040; }
  else                       { scale=3; rel=bid-s0-s1-s2;   N=144;  nqb=1; slotoff=24192; }
  const int per_b = nqb*S;
  const int b = rel / per_b;
  const int rel2 = rel - b*per_b;
  const int qblk = rel2 / S;
  const int chunk = rel2 - qblk*S;
  const int L = (N + S - 1)/S;
  const int ks = chunk*L;
  const int ke = min(N, ks + L);
  const int slotbase = slotoff + b*N;
  const float kmn = KST[(scale*2 + b)*2], kmx = KST[(scale*2 + b)*2 + 1];

  float qp[RQ], nm[RQ], den[RQ], acc[RQ][8];
  #pragma unroll
  for (int j = 0; j < RQ; ++j) {
    const int qi = qblk*1024 + tid + 256*j;
    if (qi < N) { const float qv = Q[slotbase + qi]; qp[j] = qv; nm[j] = -fmaxf(qv*kmn, qv*kmx); }
    else        { qp[j] = 0.f; nm[j] = -1e30f; }   // exp(-1e30) == 0
    den[j] = 0.f;
    #pragma unroll
    for (int c = 0; c < 8; ++c) acc[j][c] = 0.f;
  }

  for (int kt = ks; kt < ke; kt += TK) {
    const int tl = min(TK, ke - kt);
    __syncthreads();
    for (int i = tid; i < tl; i += 256) k_s[i] = K[slotbase + kt + i];
    const float4* vsrc = (const float4*)&V[(size_t)(slotbase + kt)*8];
    float4* vdst = (float4*)v_s;
    for (int i = tid; i < tl*2; i += 256) vdst[i] = vsrc[i];
    __syncthreads();
    for (int j2 = 0; j2 < tl; ++j2) {
      const float kk = k_s[j2];
      const float4 va = *(const float4*)&v_s[j2*8];
      const float4 vb = *(const float4*)&v_s[j2*8 + 4];
      #pragma unroll
      for (int j = 0; j < RQ; ++j) {
        const float e = __expf(fmaf(qp[j], kk, nm[j]));
        den[j] += e;
        acc[j][0] = fmaf(va.x, e, acc[j][0]);
        acc[j][1] = fmaf(va.y, e, acc[j][1]);
        acc[j][2] = fmaf(va.z, e, acc[j][2]);
        acc[j][3] = fmaf(va.w, e, acc[j][3]);
        acc[j][4] = fmaf(vb.x, e, acc[j][4]);
        acc[j][5] = fmaf(vb.y, e, acc[j][5]);
        acc[j][6] = fmaf(vb.z, e, acc[j][6]);
        acc[j][7] = fmaf(vb.w, e, acc[j][7]);
      }
    }
  }
  #pragma unroll
  for (int j = 0; j < RQ; ++j) {
    const int qi = qblk*1024 + tid + 256*j;
    if (qi < N) {
      const int g = slotoff + b*N + qi;
      float* pp = &PART[((size_t)g*S + chunk)*9];
      pp[0] = den[j];
      #pragma unroll
      for (int c = 0; c < 8; ++c) pp[1 + c] = acc[j][c];
    }
  }
}

__global__ LB void combine_kernel(const float* __restrict__ PART, const float* __restrict__ P,
                                  const float* wgA, const float* bgA,
                                  const float* wgB, const float* bgB,
                                  const float* wgC, const float* bgC,
                                  float* __restrict__ Y, int S) {
  const int g = blockIdx.x*256 + threadIdx.x;
  if (g >= NSLOT) return;
  const float *wg, *bg;
  if (g < 18432)      { wg = wgA; bg = bgA; }
  else if (g < 23040) { wg = wgB; bg = bgB; }
  else if (g < 24192) { wg = wgC; bg = bgC; }
  else                { wg = wgB; bg = bgB; }   // scale 3 uses cca1 (faithful to reference)
  float den = 0.f, acc[8];
  #pragma unroll
  for (int c = 0; c < 8; ++c) acc[c] = 0.f;
  const float* pp = &PART[(size_t)g*S*9];
  for (int s = 0; s < S; ++s) {
    den += pp[s*9];
    #pragma unroll
    for (int c = 0; c < 8; ++c) acc[c] += pp[s*9 + 1 + c];
  }
  const float inv = 1.0f/den;
  float o8[8];
  #pragma unroll
  for (int c = 0; c < 8; ++c) o8[c] = acc[c]*inv;
  #pragma unroll
  for (int o = 0; o < 8; ++o) {
    float y = P[(size_t)g*8 + o] + bg[o];
    #pragma unroll
    for (int c = 0; c < 8; ++c) y = fmaf(wg[o*8 + c], o8[c], y);
    Y[(size_t)g*8 + o] = y;
  }
}

template<int HS>
__device__ inline void bilerp8(float* zo, const float* Yb, int h, int w) {
  constexpr float inv = (float)HS/96.0f;
  const float sy = (h + 0.5f)*inv - 0.5f;
  const float sx = (w + 0.5f)*inv - 0.5f;
  const int iy0 = (int)floorf(sy); const float fy = sy - (float)iy0;
  const int ix0 = (int)floorf(sx); const float fx = sx - (float)ix0;
  const int y0 = min(max(iy0, 0), HS-1), y1 = min(max(iy0 + 1, 0), HS-1);
  const int x0 = min(max(ix0, 0), HS-1), x1 = min(max(ix0 + 1, 0), HS-1);
  const float* p00 = &Yb[(size_t)(y0*HS + x0)*8];
  const float* p01 = &Yb[(size_t)(y0*HS + x1)*8];
  const float* p10 = &Yb[(size_t)(y1*HS + x0)*8];
  const float* p11 = &Yb[(size_t)(y1*HS + x1)*8];
  const float w00 = (1.f-fy)*(1.f-fx), w01 = (1.f-fy)*fx, w10 = fy*(1.f-fx), w11 = fy*fx;
  #pragma unroll
  for (int c = 0; c < 8; ++c)
    zo[c] = w00*p00[c] + w01*p01[c] + w10*p10[c] + w11*p11[c];
}

__global__ LB void head_kernel(const float* __restrict__ Y,
                               const float* wl0, const float* bl0,
                               const float* bn_s, const float* bn_b,
                               const float* bn_m, const float* bn_v,
                               const float* wl1, const float* bl1,
                               float* __restrict__ out) {
  __shared__ float s_wl0[1024], s_wl1[608];
  __shared__ float s_bl0[32], s_sc[32], s_sh[32], s_bl1[19];
  const int tid = threadIdx.x;
  for (int i = tid; i < 1024; i += 256) s_wl0[i] = wl0[i];
  for (int i = tid; i < 608;  i += 256) s_wl1[i] = wl1[i];
  if (tid < 32) {
    s_bl0[tid] = bl0[tid];
    const float sc = bn_s[tid] / sqrtf(bn_v[tid] + 1e-5f);
    s_sc[tid] = sc;
    s_sh[tid] = bn_b[tid] - bn_m[tid]*sc;
  }
  if (tid < 19) s_bl1[tid] = bl1[tid];
  __syncthreads();
  const int gp = blockIdx.x*256 + tid;   // exactly 18432 threads
  const int b = (gp >= 9216) ? 1 : 0;
  const int n = gp - b*9216;
  const int h = n / 96, w = n - h*96;
  float z[32];
  {
    const float* p = &Y[(size_t)(b*9216 + n)*8];
    #pragma unroll
    for (int c = 0; c < 8; ++c) z[c] = p[c];
  }
  bilerp8<48>(z + 8,  &Y[(size_t)(18432 + b*2304)*8], h, w);
  bilerp8<24>(z + 16, &Y[(size_t)(23040 + b*576)*8],  h, w);
  bilerp8<12>(z + 24, &Y[(size_t)(24192 + b*144)*8],  h, w);
  float t[32];
  #pragma unroll
  for (int o = 0; o < 32; ++o) {
    float s = s_bl0[o];
    #pragma unroll
    for (int c = 0; c < 32; ++c) s = fmaf(s_wl0[o*32 + c], z[c], s);
    s = fmaf(s, s_sc[o], s_sh[o]);
    t[o] = fmaxf(s, 0.f);
  }
  #pragma unroll
  for (int o = 0; o < 19; ++o) {
    float s = s_bl1[o];
    #pragma unroll
    for (int c = 0; c < 32; ++c) s = fmaf(s_wl1[o*32 + c], t[c], s);
    out[((size_t)b*19 + o)*9216 + n] = s;
  }
}

extern "C" void kernel_launch(void* const* d_in, const int* in_sizes, int n_in,
                              void* d_out, int out_size, void* d_ws, size_t ws_size,
                              hipStream_t stream) {
  (void)in_sizes; (void)n_in; (void)out_size;
  const float* wq[3]; const float* bq[3]; const float* wk[3]; const float* bk[3];
  const float* wv[3]; const float* bv[3]; const float* wg[3]; const float* bg[3];
  for (int i = 0; i < 3; ++i) {
    const int base = 12 + i*8;
    wq[i] = (const float*)d_in[base + 0]; bq[i] = (const float*)d_in[base + 1];
    wk[i] = (const float*)d_in[base + 2]; bk[i] = (const float*)d_in[base + 3];
    wv[i] = (const float*)d_in[base + 4]; bv[i] = (const float*)d_in[base + 5];
    wg[i] = (const float*)d_in[base + 6]; bg[i] = (const float*)d_in[base + 7];
  }
  const int m4[4] = {0, 1, 2, 1};   // scale -> cca index (scale3 reuses cca1, faithful)

  QkvArgs qa;
  qa.x0 = (const float*)d_in[0]; qa.x1 = (const float*)d_in[1];
  qa.x2 = (const float*)d_in[2]; qa.x3 = (const float*)d_in[3];
  qa.w0 = (const float*)d_in[4];  qa.c0 = (const float*)d_in[5];
  qa.w1 = (const float*)d_in[6];  qa.c1 = (const float*)d_in[7];
  qa.w2 = (const float*)d_in[8];  qa.c2 = (const float*)d_in[9];
  qa.w3 = (const float*)d_in[10]; qa.c3 = (const float*)d_in[11];
  for (int s = 0; s < 4; ++s) {
    qa.wq[s] = wq[m4[s]]; qa.bq[s] = bq[m4[s]];
    qa.wk[s] = wk[m4[s]]; qa.bk[s] = bk[m4[s]];
    qa.wv[s] = wv[m4[s]]; qa.bv[s] = bv[m4[s]];
  }

  float* ws = (float*)d_ws;
  // workspace layout (floats): P[NSLOT*8] V[NSLOT*8] Q[NSLOT] K[NSLOT] KST[16] PART[NSLOT*9*S] Y[NSLOT*8]
  int S = 1;
  const size_t fixed = (size_t)NSLOT*8*3 + (size_t)NSLOT*2 + 16;
  const int cands[4] = {8, 4, 2, 1};
  for (int ci = 0; ci < 4; ++ci) {
    if ((fixed + (size_t)NSLOT*9*cands[ci])*sizeof(float) <= ws_size) { S = cands[ci]; break; }
  }
  float* P = ws;
  float* V = P + (size_t)NSLOT*8;
  float* Q = V + (size_t)NSLOT*8;
  float* K = Q + NSLOT;
  float* KST = K + NSLOT;
  float* PART = KST + 16;
  float* Y = PART + (size_t)NSLOT*9*S;
  qa.P = P; qa.V = V; qa.Q = Q; qa.K = K;

  qkv_kernel<<<97, 256, 0, stream>>>(qa);
  kstat_kernel<<<8, 256, 0, stream>>>(K, KST);
  attn_kernel<<<28*S, 256, 0, stream>>>(Q, K, V, KST, PART, S);
  combine_kernel<<<96, 256, 0, stream>>>(PART, P, wg[0], bg[0], wg[1], bg[1], wg[2], bg[2], Y, S);
  head_kernel<<<72, 256, 0, stream>>>(Y, (const float*)d_in[36], (const float*)d_in[37],
                                      (const float*)d_in[38], (const float*)d_in[39],
                                      (const float*)d_in[40], (const float*)d_in[41],
                                      (const float*)d_in[42], (const float*)d_in[43],
                                      (float*)d_out);
}